// Round 18
// baseline (262.605 us; speedup 1.0000x reference)
//
#include <hip/hip_runtime.h>
#include <stdint.h>

// FilteredLReLU: up2(17-tap) -> *2 -> lrelu(0.01) -> down2(17-tap), fused.
// pk_fma SWAR + block-level LDS sharing of packed f16 intermediate pairs:
//   stage A: each thread computes its 4 ga + 4 goa pairs (no halo) from
//            4 aligned float4 x loads; 4 threads add the 4 halo pairs.
//            Pairs written to LDS at stride 16B (conflict-free b128).
//   stage B: each thread b128-reads 8+8 pairs, scatters to 8 outputs.
// Cuts intermediate redundancy 2x: ~211 vs ~298 VALU ops/thread.
//
//   ge[m] = lrelu( sum fe[j]*x[m-4+j] ), go[m] = lrelu( sum fo[j]*x[m-3+j] )
//   z[t]  = sum de[j]*ge[t-4+j] + sum dd[j]*go[t-4+j]   (UP gain in fe/fo)

#define T_LEN 32768
#define R_OUT 8
#define BLK   256
#define OUTB  (BLK * R_OUT)      // 2048 outputs per block
#define BPR   (T_LEN / OUTB)     // 16 blocks per row
#define HPAIR (OUTB / 2)         // 1024 "own" pairs per array
#define NPAIR (HPAIR + 4)        // +4 halo pairs

typedef __fp16   cvt2 __attribute__((ext_vector_type(2)));  // pkrtz result
typedef _Float16 hpair __attribute__((ext_vector_type(2))); // arithmetic

__device__ __forceinline__ uint32_t pkrtz(float lo, float hi) {
    cvt2 p = __builtin_amdgcn_cvt_pkrtz(lo, hi);
    return __builtin_bit_cast(uint32_t, p);
}
__device__ __forceinline__ hpair h2(uint32_t u) {
    return __builtin_bit_cast(hpair, u);
}
__device__ __forceinline__ uint32_t u32(hpair h) {
    return __builtin_bit_cast(uint32_t, h);
}
__device__ __forceinline__ hpair pk_fma(hpair a, hpair b, hpair c) {
    return __builtin_elementwise_fma(a, b, c);
}
__device__ __forceinline__ hpair pk_lrelu(hpair v, hpair c01) {
    return __builtin_elementwise_max(v, v * c01);
}
__device__ __forceinline__ float lrelu(float v) { return fmaxf(v, 0.01f * v); }

// ---- setup: broadcast tap pairs once into ws[0..33] ----
// ws[0..8]=feB, ws[9..16]=foB, ws[17..25]=deB, ws[26..33]=ddB
__global__ void pack_taps(const float* __restrict__ up,
                          const float* __restrict__ dn,
                          uint32_t* __restrict__ ws) {
    if (threadIdx.x == 0 && blockIdx.x == 0) {
        #pragma unroll
        for (int j = 0; j < 9; ++j) {
            float fe = 2.0f * up[2*j];
            float de = dn[2*j];
            ws[j]      = pkrtz(fe, fe);
            ws[17 + j] = pkrtz(de, de);
        }
        #pragma unroll
        for (int j = 0; j < 8; ++j) {
            float fo = 2.0f * up[2*j+1];
            float dd = dn[2*j+1];
            ws[9 + j]  = pkrtz(fo, fo);
            ws[26 + j] = pkrtz(dd, dd);
        }
    }
}

__global__ __launch_bounds__(256) void flrelu_lds(
    const float* __restrict__ x,
    const float* __restrict__ up,
    const float* __restrict__ dn,
    const uint32_t* __restrict__ tw,
    float* __restrict__ out)
{
    __shared__ uint32_t sga[NPAIR];
    __shared__ uint32_t sgo[NPAIR];

    const int tid = threadIdx.x;
    const int row = blockIdx.x >> 4;            // / BPR
    const int blk = blockIdx.x & (BPR - 1);
    const int t0  = blk * OUTB;
    const int t   = t0 + tid * R_OUT;
    const float* __restrict__ xrow = x + (size_t)row * T_LEN;
    float* __restrict__ orow       = out + (size_t)row * T_LEN;

    // taps (uniform s_loads)
    hpair feB[9], foB[8], deB[9], ddB[8];
    #pragma unroll
    for (int j = 0; j < 9; ++j) { feB[j] = h2(tw[j]); deB[j] = h2(tw[17+j]); }
    #pragma unroll
    for (int j = 0; j < 8; ++j) { foB[j] = h2(tw[9+j]); ddB[j] = h2(tw[26+j]); }
    const hpair c01 = h2(pkrtz(0.01f, 0.01f));

    const bool safe = (blk == 0) || (blk == BPR - 1);

    // ---- stage A: compute own 4 ga + 4 goa pairs, write to LDS ----
    {
        float xv[16];   // x[t-8 .. t+7]
        if (!safe) {
            const float4* xp = reinterpret_cast<const float4*>(xrow + t - 8);
            #pragma unroll
            for (int k = 0; k < 4; ++k) {
                float4 v = xp[k];
                xv[4*k+0] = v.x; xv[4*k+1] = v.y;
                xv[4*k+2] = v.z; xv[4*k+3] = v.w;
            }
        } else {
            #pragma unroll
            for (int i = 0; i < 16; ++i) {
                int g = t - 8 + i;
                xv[i] = (g >= 0 && g < T_LEN) ? xrow[g] : 0.0f;
            }
        }

        uint32_t xau[8], xsu[7];
        #pragma unroll
        for (int k = 0; k < 8; ++k) xau[k] = pkrtz(xv[2*k], xv[2*k+1]);
        #pragma unroll
        for (int k = 0; k < 7; ++k)
            xsu[k] = (xau[k] >> 16) | (xau[k+1] << 16);   // v_alignbit_b32

        uint32_t ga[4], go[4];
        #pragma unroll
        for (int q = 0; q < 4; ++q) {
            hpair s = feB[0] * h2(xau[q]);
            #pragma unroll
            for (int a = 1; a < 5; ++a) s = pk_fma(feB[2*a], h2(xau[q+a]), s);
            #pragma unroll
            for (int a = 0; a < 4; ++a) s = pk_fma(feB[2*a+1], h2(xsu[q+a]), s);
            ga[q] = u32(pk_lrelu(s, c01));

            hpair r = foB[0] * h2(xsu[q]);
            #pragma unroll
            for (int a = 1; a < 4; ++a) r = pk_fma(foB[2*a], h2(xsu[q+a]), r);
            #pragma unroll
            for (int a = 0; a < 4; ++a) r = pk_fma(foB[2*a+1], h2(xau[q+a+1]), r);
            go[q] = u32(pk_lrelu(r, c01));
        }

        if (safe) {   // zero pairs whose m is outside [0, T_LEN)
            #pragma unroll
            for (int q = 0; q < 4; ++q) {
                int m0 = t - 4 + 2*q;
                uint32_t msk = ((m0 >= 0 && m0 < T_LEN) ? 0x0000FFFFu : 0u)
                             | ((m0+1 >= 0 && m0+1 < T_LEN) ? 0xFFFF0000u : 0u);
                ga[q] &= msk; go[q] &= msk;
            }
        }

        *reinterpret_cast<uint4*>(&sga[4*tid]) =
            make_uint4(ga[0], ga[1], ga[2], ga[3]);
        *reinterpret_cast<uint4*>(&sgo[4*tid]) =
            make_uint4(go[0], go[1], go[2], go[3]);
    }

    // ---- halo pairs p = 1024..1027 (4 lanes of wave 0, scalar f32) ----
    if (tid < 4) {
        float fe[9], fo[8];
        #pragma unroll
        for (int j = 0; j < 9; ++j) fe[j] = 2.0f * up[2*j];
        #pragma unroll
        for (int j = 0; j < 8; ++j) fo[j] = 2.0f * up[2*j+1];

        const int p  = HPAIR + tid;
        const int m0 = t0 - 4 + 2*p;        // t0 + 2044 + 2*tid
        float xw[10];                        // x[m0-4 .. m0+5]
        #pragma unroll
        for (int i = 0; i < 10; ++i) {
            int g = m0 - 4 + i;
            xw[i] = (g >= 0 && g < T_LEN) ? xrow[g] : 0.0f;
        }
        float g0 = 0.f, g1 = 0.f, h0 = 0.f, h1 = 0.f;
        #pragma unroll
        for (int j = 0; j < 9; ++j) { g0 = fmaf(fe[j], xw[j], g0);
                                      g1 = fmaf(fe[j], xw[j+1], g1); }
        #pragma unroll
        for (int j = 0; j < 8; ++j) { h0 = fmaf(fo[j], xw[j+1], h0);
                                      h1 = fmaf(fo[j], xw[j+2], h1); }
        g0 = lrelu(g0); g1 = lrelu(g1); h0 = lrelu(h0); h1 = lrelu(h1);
        if (!(m0   >= 0 && m0   < T_LEN)) { g0 = 0.f; h0 = 0.f; }
        if (!(m0+1 >= 0 && m0+1 < T_LEN)) { g1 = 0.f; h1 = 0.f; }
        sga[p] = pkrtz(g0, g1);
        sgo[p] = pkrtz(h0, h1);
    }

    __syncthreads();

    // ---- stage B: read 8+8 pairs, scatter to 8 outputs ----
    {
        uint4 A0 = *reinterpret_cast<const uint4*>(&sga[4*tid]);
        uint4 A1 = *reinterpret_cast<const uint4*>(&sga[4*tid + 4]);
        uint4 B0 = *reinterpret_cast<const uint4*>(&sgo[4*tid]);
        uint4 B1 = *reinterpret_cast<const uint4*>(&sgo[4*tid + 4]);
        uint32_t gaF[8] = {A0.x, A0.y, A0.z, A0.w, A1.x, A1.y, A1.z, A1.w};
        uint32_t goF[8] = {B0.x, B0.y, B0.z, B0.w, B1.x, B1.y, B1.z, B1.w};

        uint32_t gs[7], gos[7];
        #pragma unroll
        for (int k = 0; k < 7; ++k) {
            gs[k]  = (gaF[k] >> 16) | (gaF[k+1] << 16);
            gos[k] = (goF[k] >> 16) | (goF[k+1] << 16);
        }

        hpair zp[4];
        #pragma unroll
        for (int p = 0; p < 4; ++p) {
            hpair s = deB[0] * h2(gaF[p]);
            #pragma unroll
            for (int a = 1; a < 5; ++a) s = pk_fma(deB[2*a], h2(gaF[p+a]), s);
            #pragma unroll
            for (int a = 0; a < 4; ++a) s = pk_fma(deB[2*a+1], h2(gs[p+a]), s);
            #pragma unroll
            for (int a = 0; a < 4; ++a) s = pk_fma(ddB[2*a], h2(goF[p+a]), s);
            #pragma unroll
            for (int a = 0; a < 4; ++a) s = pk_fma(ddB[2*a+1], h2(gos[p+a]), s);
            zp[p] = s;
        }

        float4* op = reinterpret_cast<float4*>(orow + t);
        op[0] = make_float4((float)zp[0][0], (float)zp[0][1],
                            (float)zp[1][0], (float)zp[1][1]);
        op[1] = make_float4((float)zp[2][0], (float)zp[2][1],
                            (float)zp[3][0], (float)zp[3][1]);
    }
}

extern "C" void kernel_launch(void* const* d_in, const int* in_sizes, int n_in,
                              void* d_out, int out_size, void* d_ws, size_t ws_size,
                              hipStream_t stream) {
    const float* x  = (const float*)d_in[0];
    const float* up = (const float*)d_in[1];
    const float* dn = (const float*)d_in[2];
    float* out      = (float*)d_out;
    uint32_t* ws    = (uint32_t*)d_ws;

    pack_taps<<<1, 64, 0, stream>>>(up, dn, ws);

    const int rows   = in_sizes[0] / T_LEN;          // 2048
    const int blocks = rows * BPR;                   // 32768
    flrelu_lds<<<blocks, BLK, 0, stream>>>(x, up, dn, ws, out);
}

// Round 19
// 262.267 us; speedup vs baseline: 1.0013x; 1.0013x over previous
//
#include <hip/hip_runtime.h>
#include <stdint.h>

// FilteredLReLU: up2(17-tap) -> *2 -> lrelu(0.01) -> down2(17-tap), fused.
// pk_fma SWAR + LDS sharing of packed f16 intermediate pairs (R18 retry):
//   - NO __launch_bounds__ (R18's VGPR=16 allocation killed it)
//   - halo pairs computed in packed SWAR from tw taps (no divergent f32/
//     global-tap path in main kernel)
//   - staged x float4s pinned to force clustered loads
// stage A: thread computes 4 ga + 4 go pairs -> LDS (stride-16B b128).
// stage B: thread b128-reads 8+8 pairs, scatters to its 8 outputs.
//
//   ge[m] = lrelu( sum fe[j]*x[m-4+j] ), go[m] = lrelu( sum fo[j]*x[m-3+j] )
//   z[t]  = sum de[j]*ge[t-4+j] + sum dd[j]*go[t-4+j]   (UP gain in fe/fo)

#define T_LEN 32768
#define R_OUT 8
#define BLK   256
#define OUTB  (BLK * R_OUT)      // 2048 outputs per block
#define BPR   (T_LEN / OUTB)     // 16 blocks per row
#define HPAIR (OUTB / 2)         // 1024 own pairs
#define NPAIR (HPAIR + 4)        // +4 halo pairs

typedef __fp16   cvt2 __attribute__((ext_vector_type(2)));  // pkrtz result
typedef _Float16 hpair __attribute__((ext_vector_type(2))); // arithmetic

__device__ __forceinline__ uint32_t pkrtz(float lo, float hi) {
    cvt2 p = __builtin_amdgcn_cvt_pkrtz(lo, hi);
    return __builtin_bit_cast(uint32_t, p);
}
__device__ __forceinline__ hpair h2(uint32_t u) {
    return __builtin_bit_cast(hpair, u);
}
__device__ __forceinline__ uint32_t u32(hpair h) {
    return __builtin_bit_cast(uint32_t, h);
}
__device__ __forceinline__ hpair pk_fma(hpair a, hpair b, hpair c) {
    return __builtin_elementwise_fma(a, b, c);
}
__device__ __forceinline__ hpair pk_lrelu(hpair v, hpair c01) {
    return __builtin_elementwise_max(v, v * c01);
}
__device__ __forceinline__ void pin4(float4& v) {
    asm volatile("" : "+v"(v.x), "+v"(v.y), "+v"(v.z), "+v"(v.w));
}

// ---- setup: broadcast tap pairs once into ws[0..33] ----
// ws[0..8]=feB, ws[9..16]=foB, ws[17..25]=deB, ws[26..33]=ddB
__global__ void pack_taps(const float* __restrict__ up,
                          const float* __restrict__ dn,
                          uint32_t* __restrict__ ws) {
    if (threadIdx.x == 0 && blockIdx.x == 0) {
        #pragma unroll
        for (int j = 0; j < 9; ++j) {
            float fe = 2.0f * up[2*j];
            float de = dn[2*j];
            ws[j]      = pkrtz(fe, fe);
            ws[17 + j] = pkrtz(de, de);
        }
        #pragma unroll
        for (int j = 0; j < 8; ++j) {
            float fo = 2.0f * up[2*j+1];
            float dd = dn[2*j+1];
            ws[9 + j]  = pkrtz(fo, fo);
            ws[26 + j] = pkrtz(dd, dd);
        }
    }
}

__global__ void flrelu_lds2(
    const float* __restrict__ x,
    const uint32_t* __restrict__ tw,
    float* __restrict__ out)
{
    __shared__ uint32_t sga[NPAIR];
    __shared__ uint32_t sgo[NPAIR];

    const int tid = threadIdx.x;
    const int row = blockIdx.x >> 4;            // / BPR
    const int blk = blockIdx.x & (BPR - 1);
    const int t0  = blk * OUTB;
    const int t   = t0 + tid * R_OUT;
    const float* __restrict__ xrow = x + (size_t)row * T_LEN;
    float* __restrict__ orow       = out + (size_t)row * T_LEN;

    // taps (uniform s_loads)
    hpair feB[9], foB[8], deB[9], ddB[8];
    #pragma unroll
    for (int j = 0; j < 9; ++j) { feB[j] = h2(tw[j]); deB[j] = h2(tw[17+j]); }
    #pragma unroll
    for (int j = 0; j < 8; ++j) { foB[j] = h2(tw[9+j]); ddB[j] = h2(tw[26+j]); }
    const hpair c01 = h2(pkrtz(0.01f, 0.01f));

    const bool edge = (blk == 0) || (blk == BPR - 1);

    // ---- stage A: own 4 ga + 4 go pairs -> LDS ----
    {
        float xv[16];   // x[t-8 .. t+7]
        if (!edge) {
            const float4* xp = reinterpret_cast<const float4*>(xrow + t - 8);
            float4 v0 = xp[0], v1 = xp[1], v2 = xp[2], v3 = xp[3];
            pin4(v0); pin4(v1); pin4(v2); pin4(v3);
            xv[0]=v0.x; xv[1]=v0.y; xv[2]=v0.z; xv[3]=v0.w;
            xv[4]=v1.x; xv[5]=v1.y; xv[6]=v1.z; xv[7]=v1.w;
            xv[8]=v2.x; xv[9]=v2.y; xv[10]=v2.z; xv[11]=v2.w;
            xv[12]=v3.x; xv[13]=v3.y; xv[14]=v3.z; xv[15]=v3.w;
        } else {
            #pragma unroll
            for (int i = 0; i < 16; ++i) {
                int g = t - 8 + i;
                xv[i] = (g >= 0 && g < T_LEN) ? xrow[g] : 0.0f;
            }
        }

        uint32_t xau[8], xsu[7];
        #pragma unroll
        for (int k = 0; k < 8; ++k) xau[k] = pkrtz(xv[2*k], xv[2*k+1]);
        #pragma unroll
        for (int k = 0; k < 7; ++k)
            xsu[k] = (xau[k] >> 16) | (xau[k+1] << 16);   // v_alignbit_b32

        uint32_t ga[4], go[4];
        #pragma unroll
        for (int q = 0; q < 4; ++q) {
            hpair s = feB[0] * h2(xau[q]);
            #pragma unroll
            for (int a = 1; a < 5; ++a) s = pk_fma(feB[2*a], h2(xau[q+a]), s);
            #pragma unroll
            for (int a = 0; a < 4; ++a) s = pk_fma(feB[2*a+1], h2(xsu[q+a]), s);
            ga[q] = u32(pk_lrelu(s, c01));

            hpair r = foB[0] * h2(xsu[q]);
            #pragma unroll
            for (int a = 1; a < 4; ++a) r = pk_fma(foB[2*a], h2(xsu[q+a]), r);
            #pragma unroll
            for (int a = 0; a < 4; ++a) r = pk_fma(foB[2*a+1], h2(xau[q+a+1]), r);
            go[q] = u32(pk_lrelu(r, c01));
        }

        if (edge) {   // zero pairs whose m is outside [0, T_LEN)
            #pragma unroll
            for (int q = 0; q < 4; ++q) {
                int m0 = t - 4 + 2*q;
                uint32_t msk = ((m0 >= 0 && m0 < T_LEN) ? 0x0000FFFFu : 0u)
                             | ((m0+1 >= 0 && m0+1 < T_LEN) ? 0xFFFF0000u : 0u);
                ga[q] &= msk; go[q] &= msk;
            }
        }

        *reinterpret_cast<uint4*>(&sga[4*tid]) =
            make_uint4(ga[0], ga[1], ga[2], ga[3]);
        *reinterpret_cast<uint4*>(&sgo[4*tid]) =
            make_uint4(go[0], go[1], go[2], go[3]);
    }

    // ---- halo pairs p = 1024..1027: packed SWAR on 4 lanes ----
    if (tid < 4) {
        // window region x[t0+2040 .. t0+2055]; in-range except last block
        float xw[16];
        const int base = t0 + OUTB - 8;          // t0 + 2040
        if (blk != BPR - 1) {
            const float4* hp = reinterpret_cast<const float4*>(xrow + base);
            float4 v0 = hp[0], v1 = hp[1], v2 = hp[2], v3 = hp[3];
            xw[0]=v0.x; xw[1]=v0.y; xw[2]=v0.z; xw[3]=v0.w;
            xw[4]=v1.x; xw[5]=v1.y; xw[6]=v1.z; xw[7]=v1.w;
            xw[8]=v2.x; xw[9]=v2.y; xw[10]=v2.z; xw[11]=v2.w;
            xw[12]=v3.x; xw[13]=v3.y; xw[14]=v3.z; xw[15]=v3.w;
        } else {
            #pragma unroll
            for (int i = 0; i < 16; ++i) {
                int g = base + i;
                xw[i] = (g < T_LEN) ? xrow[g] : 0.0f;
            }
        }

        const int off = 2 * tid;                 // window start within xw
        uint32_t ha[5], hs[4];
        #pragma unroll
        for (int k = 0; k < 5; ++k) ha[k] = pkrtz(xw[off+2*k], xw[off+2*k+1]);
        #pragma unroll
        for (int k = 0; k < 4; ++k) hs[k] = pkrtz(xw[off+2*k+1], xw[off+2*k+2]);

        hpair s = feB[0] * h2(ha[0]);
        #pragma unroll
        for (int a = 1; a < 5; ++a) s = pk_fma(feB[2*a], h2(ha[a]), s);
        #pragma unroll
        for (int a = 0; a < 4; ++a) s = pk_fma(feB[2*a+1], h2(hs[a]), s);
        uint32_t ua = u32(pk_lrelu(s, c01));

        hpair r = foB[0] * h2(hs[0]);
        #pragma unroll
        for (int a = 1; a < 4; ++a) r = pk_fma(foB[2*a], h2(hs[a]), r);
        #pragma unroll
        for (int a = 0; a < 4; ++a) r = pk_fma(foB[2*a+1], h2(ha[a+1]), r);
        uint32_t ug = u32(pk_lrelu(r, c01));

        const int m0 = t0 + OUTB - 4 + 2*tid;    // pair positions (m0, m0+1)
        uint32_t msk = ((m0   < T_LEN) ? 0x0000FFFFu : 0u)
                     | ((m0+1 < T_LEN) ? 0xFFFF0000u : 0u);
        sga[HPAIR + tid] = ua & msk;
        sgo[HPAIR + tid] = ug & msk;
    }

    __syncthreads();

    // ---- stage B: read 8+8 pairs, scatter to 8 outputs ----
    {
        uint4 A0 = *reinterpret_cast<const uint4*>(&sga[4*tid]);
        uint4 A1 = *reinterpret_cast<const uint4*>(&sga[4*tid + 4]);
        uint4 B0 = *reinterpret_cast<const uint4*>(&sgo[4*tid]);
        uint4 B1 = *reinterpret_cast<const uint4*>(&sgo[4*tid + 4]);
        uint32_t gaF[8] = {A0.x, A0.y, A0.z, A0.w, A1.x, A1.y, A1.z, A1.w};
        uint32_t goF[8] = {B0.x, B0.y, B0.z, B0.w, B1.x, B1.y, B1.z, B1.w};

        uint32_t gs[7], gos[7];
        #pragma unroll
        for (int k = 0; k < 7; ++k) {
            gs[k]  = (gaF[k] >> 16) | (gaF[k+1] << 16);
            gos[k] = (goF[k] >> 16) | (goF[k+1] << 16);
        }

        hpair zp[4];
        #pragma unroll
        for (int p = 0; p < 4; ++p) {
            hpair s = deB[0] * h2(gaF[p]);
            #pragma unroll
            for (int a = 1; a < 5; ++a) s = pk_fma(deB[2*a], h2(gaF[p+a]), s);
            #pragma unroll
            for (int a = 0; a < 4; ++a) s = pk_fma(deB[2*a+1], h2(gs[p+a]), s);
            #pragma unroll
            for (int a = 0; a < 4; ++a) s = pk_fma(ddB[2*a], h2(goF[p+a]), s);
            #pragma unroll
            for (int a = 0; a < 4; ++a) s = pk_fma(ddB[2*a+1], h2(gos[p+a]), s);
            zp[p] = s;
        }

        float4* op = reinterpret_cast<float4*>(orow + t);
        op[0] = make_float4((float)zp[0][0], (float)zp[0][1],
                            (float)zp[1][0], (float)zp[1][1]);
        op[1] = make_float4((float)zp[2][0], (float)zp[2][1],
                            (float)zp[3][0], (float)zp[3][1]);
    }
}

extern "C" void kernel_launch(void* const* d_in, const int* in_sizes, int n_in,
                              void* d_out, int out_size, void* d_ws, size_t ws_size,
                              hipStream_t stream) {
    const float* x  = (const float*)d_in[0];
    const float* up = (const float*)d_in[1];
    const float* dn = (const float*)d_in[2];
    float* out      = (float*)d_out;
    uint32_t* ws    = (uint32_t*)d_ws;

    pack_taps<<<1, 64, 0, stream>>>(up, dn, ws);

    const int rows   = in_sizes[0] / T_LEN;          // 2048
    const int blocks = rows * BPR;                   // 32768
    flrelu_lds2<<<blocks, BLK, 0, stream>>>(x, ws, out);
}

// Round 20
// 162.575 us; speedup vs baseline: 1.6153x; 1.6132x over previous
//
#include <hip/hip_runtime.h>
#include <stdint.h>

// FilteredLReLU via matrix cores: both 17-tap polyphase convs are banded
// Toeplitz matmuls -> mfma_f32_16x16x32_bf16.
//   up:   G[i][c]=ge[U+16c+i] = sum_k A_e[i][k]*B[k][c],  A_e[i][k]=fe[k-i],
//         B[k][c]=x_bf16[(U-4)+16c+k]   (odd phase: A_o[i][k]=fo[k-i-1], same B)
//   down: Z[i][c]=z[W'+16c+i] = A_de*B_ge + A_dd*B_go,
//         B_ge[k][c]=ge[(W'-4)+16c+k]
// k-mapping inside fragments cancels between A and B (contraction), so only
// row/col=lane&15 and the m89-verified D layout (col=lane&15,row=4*(lane>>4)+reg)
// are assumed. D->B relayout via small per-wave LDS arrays (no barriers).
// Each wave: 1024 outputs = 4 output sets + 1 halo set; row-edge waves (2/32)
// take a guarded scalar path.

#define T_LEN 32768

typedef float        f32x4  __attribute__((ext_vector_type(4)));
typedef short        bf16x8 __attribute__((ext_vector_type(8)));
typedef unsigned int u32x4  __attribute__((ext_vector_type(4)));

__device__ __forceinline__ uint32_t cvt_pk_bf16(float lo, float hi) {
    uint32_t r;
    asm("v_cvt_pk_bf16_f32 %0, %1, %2" : "=v"(r) : "v"(lo), "v"(hi));
    return r;
}
__device__ __forceinline__ float lrelu(float v) { return fmaxf(v, 0.01f * v); }

// ---- setup: 4 A-fragment tables (A_e, A_o, A_de, A_dd), 64 lanes x 4 dwords ----
__global__ void build_afrags(const float* __restrict__ up,
                             const float* __restrict__ dn,
                             uint32_t* __restrict__ ws) {
    const int l = threadIdx.x;
    if (l >= 64 || blockIdx.x != 0) return;
    float fe[9], fo[8], de[9], dd[8];
    #pragma unroll
    for (int j = 0; j < 9; ++j) { fe[j] = 2.0f*up[2*j]; de[j] = dn[2*j]; }
    #pragma unroll
    for (int j = 0; j < 8; ++j) { fo[j] = 2.0f*up[2*j+1]; dd[j] = dn[2*j+1]; }
    const int i = l & 15, g = l >> 4;
    #pragma unroll
    for (int ep = 0; ep < 4; ++ep) {
        float v[4][2];
        #pragma unroll
        for (int h = 0; h < 2; ++h) {
            const int e = 2*ep + h;
            const int k = 8*g + e;          // k-mapping; main kernel matches
            const int j = k - i;
            float ve = 0.f, vo = 0.f, vde = 0.f, vdd = 0.f;
            #pragma unroll
            for (int jj = 0; jj < 9; ++jj)
                if (j == jj) { ve = fe[jj]; vde = de[jj]; }
            #pragma unroll
            for (int jj = 0; jj < 8; ++jj) {
                if (j - 1 == jj) vo  = fo[jj];
                if (j == jj)     vdd = dd[jj];
            }
            v[0][h] = ve; v[1][h] = vo; v[2][h] = vde; v[3][h] = vdd;
        }
        #pragma unroll
        for (int m = 0; m < 4; ++m)
            ws[m*256 + l*4 + ep] = cvt_pk_bf16(v[m][0], v[m][1]);
    }
}

__global__ void flrelu_mfma(const float* __restrict__ x,
                            const float* __restrict__ up,
                            const float* __restrict__ dn,
                            const uint32_t* __restrict__ aws,
                            float* __restrict__ out)
{
    __shared__ ushort sge[4][1280];   // per-wave ge[(W-4)+e], bf16
    __shared__ ushort sgo[4][1280];

    const int lane = threadIdx.x & 63;
    const int wv   = threadIdx.x >> 6;
    const int row  = blockIdx.x >> 3;
    const int seg  = blockIdx.x & 7;
    const int W    = seg * 4096 + wv * 1024;
    const float* __restrict__ xrow = x + (size_t)row * T_LEN;
    float* __restrict__ orow       = out + (size_t)row * T_LEN;

    if (W == 0 || W == T_LEN - 1024) {
        // ---- guarded scalar path: 16 outputs per lane ----
        const int t = W + lane * 16;
        float fe[9], fo[8], de[9], dd[8];
        #pragma unroll
        for (int j = 0; j < 9; ++j) { fe[j] = 2.f*up[2*j]; de[j] = dn[2*j]; }
        #pragma unroll
        for (int j = 0; j < 8; ++j) { fo[j] = 2.f*up[2*j+1]; dd[j] = dn[2*j+1]; }
        float xv[32];
        #pragma unroll
        for (int i2 = 0; i2 < 32; ++i2) {
            int gx = t - 8 + i2;
            xv[i2] = (gx >= 0 && gx < T_LEN) ? xrow[gx] : 0.0f;
        }
        float acc[16];
        #pragma unroll
        for (int r = 0; r < 16; ++r) acc[r] = 0.0f;
        #pragma unroll
        for (int ml = 0; ml < 24; ++ml) {
            float ae = 0.0f;
            #pragma unroll
            for (int j = 0; j < 9; ++j) ae = fmaf(fe[j], xv[ml+j], ae);
            float gg = lrelu(ae);
            int m = t - 4 + ml;
            if (m < 0 || m >= T_LEN) gg = 0.0f;   // dn conv zero-pads y
            #pragma unroll
            for (int r = 0; r < 16; ++r)
                if (r >= ml - 8 && r <= ml) acc[r] = fmaf(de[ml-r], gg, acc[r]);
            if (ml < 23) {
                float ao = 0.0f;
                #pragma unroll
                for (int j = 0; j < 8; ++j) ao = fmaf(fo[j], xv[ml+1+j], ao);
                float hh = lrelu(ao);
                if (m < 0 || m >= T_LEN) hh = 0.0f;
                #pragma unroll
                for (int r = 0; r < 16; ++r)
                    if (r >= ml - 7 && r <= ml) acc[r] = fmaf(dd[ml-r], hh, acc[r]);
            }
        }
        float4* op = reinterpret_cast<float4*>(orow + t);
        #pragma unroll
        for (int k2 = 0; k2 < 4; ++k2)
            op[k2] = make_float4(acc[4*k2+0], acc[4*k2+1], acc[4*k2+2], acc[4*k2+3]);
        return;
    }

    // ---- MFMA path (interior waves: all windows fully in-range) ----
    const u32x4* at = reinterpret_cast<const u32x4*>(aws);
    const bf16x8 Ae  = __builtin_bit_cast(bf16x8, at[0*64 + lane]);
    const bf16x8 Ao  = __builtin_bit_cast(bf16x8, at[1*64 + lane]);
    const bf16x8 Ade = __builtin_bit_cast(bf16x8, at[2*64 + lane]);
    const bf16x8 Add = __builtin_bit_cast(bf16x8, at[3*64 + lane]);

    const int c = lane & 15, g = lane >> 4;
    const f32x4 zero = {0.f, 0.f, 0.f, 0.f};

    // stage A: 4 output sets + 1 halo set of intermediates -> LDS
    #pragma unroll
    for (int s = 0; s < 5; ++s) {
        const float* xp = xrow + (W - 8) + 256*s + 16*c + 8*g;
        float4 a = *reinterpret_cast<const float4*>(xp);
        float4 b = *reinterpret_cast<const float4*>(xp + 4);
        u32x4 bw;
        bw.x = cvt_pk_bf16(a.x, a.y); bw.y = cvt_pk_bf16(a.z, a.w);
        bw.z = cvt_pk_bf16(b.x, b.y); bw.w = cvt_pk_bf16(b.z, b.w);
        const bf16x8 Bx = __builtin_bit_cast(bf16x8, bw);

        f32x4 de_ = __builtin_amdgcn_mfma_f32_16x16x32_bf16(Ae, Bx, zero, 0, 0, 0);
        f32x4 do_ = __builtin_amdgcn_mfma_f32_16x16x32_bf16(Ao, Bx, zero, 0, 0, 0);

        const uint32_t e0 = cvt_pk_bf16(lrelu(de_[0]), lrelu(de_[1]));
        const uint32_t e1 = cvt_pk_bf16(lrelu(de_[2]), lrelu(de_[3]));
        const uint32_t o0 = cvt_pk_bf16(lrelu(do_[0]), lrelu(do_[1]));
        const uint32_t o1 = cvt_pk_bf16(lrelu(do_[2]), lrelu(do_[3]));

        const int elem = 256*s + 16*c + 4*g;      // pos - (W-4)
        *reinterpret_cast<uint2*>(&sge[wv][elem]) = make_uint2(e0, e1);
        *reinterpret_cast<uint2*>(&sgo[wv][elem]) = make_uint2(o0, o1);
    }

    // stage B: down-conv, 4 output sets (same-wave LDS -> no barrier)
    #pragma unroll
    for (int s = 0; s < 4; ++s) {
        const int elem = 256*s + 16*c + 8*g;
        const bf16x8 Bg = __builtin_bit_cast(bf16x8,
            *reinterpret_cast<const u32x4*>(&sge[wv][elem]));
        const bf16x8 Bo = __builtin_bit_cast(bf16x8,
            *reinterpret_cast<const u32x4*>(&sgo[wv][elem]));
        f32x4 dz = __builtin_amdgcn_mfma_f32_16x16x32_bf16(Ade, Bg, zero, 0, 0, 0);
        dz       = __builtin_amdgcn_mfma_f32_16x16x32_bf16(Add, Bo, dz,   0, 0, 0);
        *reinterpret_cast<float4*>(orow + W + 256*s + 16*c + 4*g) =
            make_float4(dz[0], dz[1], dz[2], dz[3]);
    }
}

extern "C" void kernel_launch(void* const* d_in, const int* in_sizes, int n_in,
                              void* d_out, int out_size, void* d_ws, size_t ws_size,
                              hipStream_t stream) {
    const float* x  = (const float*)d_in[0];
    const float* up = (const float*)d_in[1];
    const float* dn = (const float*)d_in[2];
    float* out      = (float*)d_out;
    uint32_t* ws    = (uint32_t*)d_ws;

    build_afrags<<<1, 64, 0, stream>>>(up, dn, ws);

    const int rows   = in_sizes[0] / T_LEN;      // 2048
    const int blocks = rows * 8;                 // 4096 outputs per block
    flrelu_mfma<<<blocks, 256, 0, stream>>>(x, up, dn, ws, out);
}

// Round 21
// 156.197 us; speedup vs baseline: 1.6812x; 1.0408x over previous
//
#include <hip/hip_runtime.h>
#include <stdint.h>

// FilteredLReLU via matrix cores (R20 structure, verified absmax 4.9e-4)
// + load-parallelization fix: all 10 staging float4s issued up-front and
// pinned live (first wait = vmcnt(9), not vmcnt(0)) so HBM/L2 latency is
// paid once per wave, not 10x. Stage B ds_reads likewise batched.
//
//   up:   G[i][c]=ge[U+16c+i] = A_e x B,  A_e[i][k]=fe[k-i],
//         B[k][c]=x_bf16[(U-4)+16c+k]   (odd: A_o[i][k]=fo[k-i-1], same B)
//   down: Z = A_de x B_ge + A_dd x B_go
// k-mapping cancels between A and B; assumes row/col=lane&15 and the
// m89-verified D layout (col=lane&15, row=4*(lane>>4)+reg).

#define T_LEN 32768

typedef float        f32x4  __attribute__((ext_vector_type(4)));
typedef short        bf16x8 __attribute__((ext_vector_type(8)));
typedef unsigned int u32x4  __attribute__((ext_vector_type(4)));

__device__ __forceinline__ uint32_t cvt_pk_bf16(float lo, float hi) {
    uint32_t r;
    asm("v_cvt_pk_bf16_f32 %0, %1, %2" : "=v"(r) : "v"(lo), "v"(hi));
    return r;
}
__device__ __forceinline__ float lrelu(float v) { return fmaxf(v, 0.01f * v); }
__device__ __forceinline__ void pin4(float4& v) {
    asm volatile("" : "+v"(v.x), "+v"(v.y), "+v"(v.z), "+v"(v.w));
}

// ---- setup: 4 A-fragment tables (A_e, A_o, A_de, A_dd), 64 lanes x 4 dwords ----
__global__ void build_afrags(const float* __restrict__ up,
                             const float* __restrict__ dn,
                             uint32_t* __restrict__ ws) {
    const int l = threadIdx.x;
    if (l >= 64 || blockIdx.x != 0) return;
    float fe[9], fo[8], de[9], dd[8];
    #pragma unroll
    for (int j = 0; j < 9; ++j) { fe[j] = 2.0f*up[2*j]; de[j] = dn[2*j]; }
    #pragma unroll
    for (int j = 0; j < 8; ++j) { fo[j] = 2.0f*up[2*j+1]; dd[j] = dn[2*j+1]; }
    const int i = l & 15, g = l >> 4;
    #pragma unroll
    for (int ep = 0; ep < 4; ++ep) {
        float v[4][2];
        #pragma unroll
        for (int h = 0; h < 2; ++h) {
            const int e = 2*ep + h;
            const int k = 8*g + e;          // k-mapping; main kernel matches
            const int j = k - i;
            float ve = 0.f, vo = 0.f, vde = 0.f, vdd = 0.f;
            #pragma unroll
            for (int jj = 0; jj < 9; ++jj)
                if (j == jj) { ve = fe[jj]; vde = de[jj]; }
            #pragma unroll
            for (int jj = 0; jj < 8; ++jj) {
                if (j - 1 == jj) vo  = fo[jj];
                if (j == jj)     vdd = dd[jj];
            }
            v[0][h] = ve; v[1][h] = vo; v[2][h] = vde; v[3][h] = vdd;
        }
        #pragma unroll
        for (int m = 0; m < 4; ++m)
            ws[m*256 + l*4 + ep] = cvt_pk_bf16(v[m][0], v[m][1]);
    }
}

__global__ void flrelu_mfma2(const float* __restrict__ x,
                             const float* __restrict__ up,
                             const float* __restrict__ dn,
                             const uint32_t* __restrict__ aws,
                             float* __restrict__ out)
{
    __shared__ ushort sge[4][1280];   // per-wave ge[(W-4)+e], bf16
    __shared__ ushort sgo[4][1280];

    const int lane = threadIdx.x & 63;
    const int wv   = threadIdx.x >> 6;
    const int row  = blockIdx.x >> 3;
    const int seg  = blockIdx.x & 7;
    const int W    = seg * 4096 + wv * 1024;
    const float* __restrict__ xrow = x + (size_t)row * T_LEN;
    float* __restrict__ orow       = out + (size_t)row * T_LEN;

    if (W == 0 || W == T_LEN - 1024) {
        // ---- guarded scalar path (2 waves per row) ----
        const int t = W + lane * 16;
        float fe[9], fo[8], de[9], dd[8];
        #pragma unroll
        for (int j = 0; j < 9; ++j) { fe[j] = 2.f*up[2*j]; de[j] = dn[2*j]; }
        #pragma unroll
        for (int j = 0; j < 8; ++j) { fe[0]=fe[0], fo[j] = 2.f*up[2*j+1], dd[j] = dn[2*j+1]; }
        float xv[32];
        #pragma unroll
        for (int i2 = 0; i2 < 32; ++i2) {
            int gx = t - 8 + i2;
            xv[i2] = (gx >= 0 && gx < T_LEN) ? xrow[gx] : 0.0f;
        }
        float acc[16];
        #pragma unroll
        for (int r = 0; r < 16; ++r) acc[r] = 0.0f;
        #pragma unroll
        for (int ml = 0; ml < 24; ++ml) {
            float ae = 0.0f;
            #pragma unroll
            for (int j = 0; j < 9; ++j) ae = fmaf(fe[j], xv[ml+j], ae);
            float gg = lrelu(ae);
            int m = t - 4 + ml;
            if (m < 0 || m >= T_LEN) gg = 0.0f;   // dn conv zero-pads y
            #pragma unroll
            for (int r = 0; r < 16; ++r)
                if (r >= ml - 8 && r <= ml) acc[r] = fmaf(de[ml-r], gg, acc[r]);
            if (ml < 23) {
                float ao = 0.0f;
                #pragma unroll
                for (int j = 0; j < 8; ++j) ao = fmaf(fo[j], xv[ml+1+j], ao);
                float hh = lrelu(ao);
                if (m < 0 || m >= T_LEN) hh = 0.0f;
                #pragma unroll
                for (int r = 0; r < 16; ++r)
                    if (r >= ml - 7 && r <= ml) acc[r] = fmaf(dd[ml-r], hh, acc[r]);
            }
        }
        float4* op = reinterpret_cast<float4*>(orow + t);
        #pragma unroll
        for (int k2 = 0; k2 < 4; ++k2)
            op[k2] = make_float4(acc[4*k2+0], acc[4*k2+1], acc[4*k2+2], acc[4*k2+3]);
        return;
    }

    // ---- MFMA path (interior waves) ----
    const u32x4* at = reinterpret_cast<const u32x4*>(aws);
    const bf16x8 Ae  = __builtin_bit_cast(bf16x8, at[0*64 + lane]);
    const bf16x8 Ao  = __builtin_bit_cast(bf16x8, at[1*64 + lane]);
    const bf16x8 Ade = __builtin_bit_cast(bf16x8, at[2*64 + lane]);
    const bf16x8 Add = __builtin_bit_cast(bf16x8, at[3*64 + lane]);

    const int c = lane & 15, g = lane >> 4;
    const f32x4 zero = {0.f, 0.f, 0.f, 0.f};

    // prefetch ALL staging x (10 float4) before any use; pin after issue
    const float* bp = xrow + (W - 8) + 16*c + 8*g;
    float4 L[10];
    #pragma unroll
    for (int s = 0; s < 5; ++s) {
        L[2*s]     = *reinterpret_cast<const float4*>(bp + 256*s);
        L[2*s + 1] = *reinterpret_cast<const float4*>(bp + 256*s + 4);
    }
    #pragma unroll
    for (int k = 0; k < 10; ++k) pin4(L[k]);

    // stage A: 5 sets of intermediates -> LDS
    #pragma unroll
    for (int s = 0; s < 5; ++s) {
        u32x4 bw;
        bw.x = cvt_pk_bf16(L[2*s].x,   L[2*s].y);
        bw.y = cvt_pk_bf16(L[2*s].z,   L[2*s].w);
        bw.z = cvt_pk_bf16(L[2*s+1].x, L[2*s+1].y);
        bw.w = cvt_pk_bf16(L[2*s+1].z, L[2*s+1].w);
        const bf16x8 Bx = __builtin_bit_cast(bf16x8, bw);

        f32x4 de_ = __builtin_amdgcn_mfma_f32_16x16x32_bf16(Ae, Bx, zero, 0, 0, 0);
        f32x4 do_ = __builtin_amdgcn_mfma_f32_16x16x32_bf16(Ao, Bx, zero, 0, 0, 0);

        const uint32_t e0 = cvt_pk_bf16(lrelu(de_[0]), lrelu(de_[1]));
        const uint32_t e1 = cvt_pk_bf16(lrelu(de_[2]), lrelu(de_[3]));
        const uint32_t o0 = cvt_pk_bf16(lrelu(do_[0]), lrelu(do_[1]));
        const uint32_t o1 = cvt_pk_bf16(lrelu(do_[2]), lrelu(do_[3]));

        const int elem = 256*s + 16*c + 4*g;      // pos - (W-4)
        *reinterpret_cast<uint2*>(&sge[wv][elem]) = make_uint2(e0, e1);
        *reinterpret_cast<uint2*>(&sgo[wv][elem]) = make_uint2(o0, o1);
    }

    // stage B: batch all LDS reads, then MFMAs, then stores
    u32x4 RG[4], RO[4];
    #pragma unroll
    for (int s = 0; s < 4; ++s) {
        const int elem = 256*s + 16*c + 8*g;
        RG[s] = *reinterpret_cast<const u32x4*>(&sge[wv][elem]);
        RO[s] = *reinterpret_cast<const u32x4*>(&sgo[wv][elem]);
    }
    #pragma unroll
    for (int s = 0; s < 4; ++s) {
        const bf16x8 Bg = __builtin_bit_cast(bf16x8, RG[s]);
        const bf16x8 Bo = __builtin_bit_cast(bf16x8, RO[s]);
        f32x4 dz = __builtin_amdgcn_mfma_f32_16x16x32_bf16(Ade, Bg, zero, 0, 0, 0);
        dz       = __builtin_amdgcn_mfma_f32_16x16x32_bf16(Add, Bo, dz,   0, 0, 0);
        *reinterpret_cast<float4*>(orow + W + 256*s + 16*c + 4*g) =
            make_float4(dz[0], dz[1], dz[2], dz[3]);
    }
}

extern "C" void kernel_launch(void* const* d_in, const int* in_sizes, int n_in,
                              void* d_out, int out_size, void* d_ws, size_t ws_size,
                              hipStream_t stream) {
    const float* x  = (const float*)d_in[0];
    const float* up = (const float*)d_in[1];
    const float* dn = (const float*)d_in[2];
    float* out      = (float*)d_out;
    uint32_t* ws    = (uint32_t*)d_ws;

    build_afrags<<<1, 64, 0, stream>>>(up, dn, ws);

    const int rows   = in_sizes[0] / T_LEN;      // 2048
    const int blocks = rows * 8;                 // 4096 outputs per block
    flrelu_mfma2<<<blocks, 256, 0, stream>>>(x, up, dn, ws, out);
}

// Round 22
// 151.530 us; speedup vs baseline: 1.7330x; 1.0308x over previous
//
#include <hip/hip_runtime.h>
#include <stdint.h>

// FilteredLReLU via matrix cores (R20 numerics, verified absmax 4.9e-4)
// + global_load_lds x-staging: the 8 interior staging loads go straight
// HBM->LDS (no VGPRs, compiler can't serialize them), drained by ONE
// vmcnt(0); halo set (2 loads) via registers. Fixes the 10x-serialized-
// load latency that left R20/R21 at 15% VALUBusy / 4% MfmaUtil.
//
//   up:   G[i][c]=ge[U+16c+i] = A_e x B,  A_e[i][k]=fe[k-i],
//         B[k][c]=x_bf16[(U-4)+16c+k]   (odd: A_o[i][k]=fo[k-i-1], same B)
//   down: Z = A_de x B_ge + A_dd x B_go
// k-mapping cancels between A and B; assumes row/col=lane&15 and the
// m89-verified D layout (col=lane&15, row=4*(lane>>4)+reg).

#define T_LEN 32768

typedef float        f32x4  __attribute__((ext_vector_type(4)));
typedef short        bf16x8 __attribute__((ext_vector_type(8)));
typedef unsigned int u32x4  __attribute__((ext_vector_type(4)));

__device__ __forceinline__ uint32_t cvt_pk_bf16(float lo, float hi) {
    uint32_t r;
    asm("v_cvt_pk_bf16_f32 %0, %1, %2" : "=v"(r) : "v"(lo), "v"(hi));
    return r;
}
__device__ __forceinline__ float lrelu(float v) { return fmaxf(v, 0.01f * v); }
__device__ __forceinline__ void pin4(float4& v) {
    asm volatile("" : "+v"(v.x), "+v"(v.y), "+v"(v.z), "+v"(v.w));
}
// async HBM->LDS, 16B/lane: per-lane global src, wave-uniform LDS base,
// HW writes lane i at base + i*16 (m104 semantics).
__device__ __forceinline__ void gl_lds16(const float* g, void* l) {
    __builtin_amdgcn_global_load_lds(
        (const __attribute__((address_space(1))) uint32_t*)g,
        (__attribute__((address_space(3))) uint32_t*)l, 16, 0, 0);
}

// ---- setup: 4 A-fragment tables (A_e, A_o, A_de, A_dd), 64 lanes x 4 dwords ----
__global__ void build_afrags(const float* __restrict__ up,
                             const float* __restrict__ dn,
                             uint32_t* __restrict__ ws) {
    const int l = threadIdx.x;
    if (l >= 64 || blockIdx.x != 0) return;
    float fe[9], fo[8], de[9], dd[8];
    #pragma unroll
    for (int j = 0; j < 9; ++j) { fe[j] = 2.0f*up[2*j]; de[j] = dn[2*j]; }
    #pragma unroll
    for (int j = 0; j < 8; ++j) { fo[j] = 2.0f*up[2*j+1]; dd[j] = dn[2*j+1]; }
    const int i = l & 15, g = l >> 4;
    #pragma unroll
    for (int ep = 0; ep < 4; ++ep) {
        float v[4][2];
        #pragma unroll
        for (int h = 0; h < 2; ++h) {
            const int e = 2*ep + h;
            const int k = 8*g + e;          // k-mapping; main kernel matches
            const int j = k - i;
            float ve = 0.f, vo = 0.f, vde = 0.f, vdd = 0.f;
            #pragma unroll
            for (int jj = 0; jj < 9; ++jj)
                if (j == jj) { ve = fe[jj]; vde = de[jj]; }
            #pragma unroll
            for (int jj = 0; jj < 8; ++jj) {
                if (j - 1 == jj) vo  = fo[jj];
                if (j == jj)     vdd = dd[jj];
            }
            v[0][h] = ve; v[1][h] = vo; v[2][h] = vde; v[3][h] = vdd;
        }
        #pragma unroll
        for (int m = 0; m < 4; ++m)
            ws[m*256 + l*4 + ep] = cvt_pk_bf16(v[m][0], v[m][1]);
    }
}

__global__ void flrelu_mfma3(const float* __restrict__ x,
                             const float* __restrict__ up,
                             const float* __restrict__ dn,
                             const uint32_t* __restrict__ aws,
                             float* __restrict__ out)
{
    // per-wave x staging: 8 slots x 64 lanes x 16B (sets 0..3)
    __shared__ __align__(16) float  xls[4][8][64][4];   // 32768 B
    __shared__ __align__(16) ushort sge[4][1280];       // 10240 B
    __shared__ __align__(16) ushort sgo[4][1280];       // 10240 B

    const int lane = threadIdx.x & 63;
    const int wv   = threadIdx.x >> 6;
    const int row  = blockIdx.x >> 3;
    const int seg  = blockIdx.x & 7;
    const int W    = seg * 4096 + wv * 1024;
    const float* __restrict__ xrow = x + (size_t)row * T_LEN;
    float* __restrict__ orow       = out + (size_t)row * T_LEN;

    if (W == 0 || W == T_LEN - 1024) {
        // ---- guarded scalar path (2 waves per row) ----
        const int t = W + lane * 16;
        float fe[9], fo[8], de[9], dd[8];
        #pragma unroll
        for (int j = 0; j < 9; ++j) { fe[j] = 2.f*up[2*j]; de[j] = dn[2*j]; }
        #pragma unroll
        for (int j = 0; j < 8; ++j) { fo[j] = 2.f*up[2*j+1]; dd[j] = dn[2*j+1]; }
        float xv[32];
        #pragma unroll
        for (int i2 = 0; i2 < 32; ++i2) {
            int gx = t - 8 + i2;
            xv[i2] = (gx >= 0 && gx < T_LEN) ? xrow[gx] : 0.0f;
        }
        float acc[16];
        #pragma unroll
        for (int r = 0; r < 16; ++r) acc[r] = 0.0f;
        #pragma unroll
        for (int ml = 0; ml < 24; ++ml) {
            float ae = 0.0f;
            #pragma unroll
            for (int j = 0; j < 9; ++j) ae = fmaf(fe[j], xv[ml+j], ae);
            float gg = lrelu(ae);
            int m = t - 4 + ml;
            if (m < 0 || m >= T_LEN) gg = 0.0f;   // dn conv zero-pads y
            #pragma unroll
            for (int r = 0; r < 16; ++r)
                if (r >= ml - 8 && r <= ml) acc[r] = fmaf(de[ml-r], gg, acc[r]);
            if (ml < 23) {
                float ao = 0.0f;
                #pragma unroll
                for (int j = 0; j < 8; ++j) ao = fmaf(fo[j], xv[ml+1+j], ao);
                float hh = lrelu(ao);
                if (m < 0 || m >= T_LEN) hh = 0.0f;
                #pragma unroll
                for (int r = 0; r < 16; ++r)
                    if (r >= ml - 7 && r <= ml) acc[r] = fmaf(dd[ml-r], hh, acc[r]);
            }
        }
        float4* op = reinterpret_cast<float4*>(orow + t);
        #pragma unroll
        for (int k2 = 0; k2 < 4; ++k2)
            op[k2] = make_float4(acc[4*k2+0], acc[4*k2+1], acc[4*k2+2], acc[4*k2+3]);
        return;
    }

    // ---- MFMA path (interior waves) ----
    const u32x4* at = reinterpret_cast<const u32x4*>(aws);
    const bf16x8 Ae  = __builtin_bit_cast(bf16x8, at[0*64 + lane]);
    const bf16x8 Ao  = __builtin_bit_cast(bf16x8, at[1*64 + lane]);
    const bf16x8 Ade = __builtin_bit_cast(bf16x8, at[2*64 + lane]);
    const bf16x8 Add = __builtin_bit_cast(bf16x8, at[3*64 + lane]);

    const int c = lane & 15, g = lane >> 4;
    const f32x4 zero = {0.f, 0.f, 0.f, 0.f};

    // issue ALL staging: 8 async HBM->LDS (sets 0..3) + 2 reg loads (set 4)
    const float* bp = xrow + (W - 8) + 16*c + 8*g;
    #pragma unroll
    for (int s = 0; s < 4; ++s) {
        gl_lds16(bp + 256*s,     &xls[wv][2*s][0][0]);
        gl_lds16(bp + 256*s + 4, &xls[wv][2*s+1][0][0]);
    }
    float4 H0 = *reinterpret_cast<const float4*>(bp + 1024);
    float4 H1 = *reinterpret_cast<const float4*>(bp + 1028);
    pin4(H0); pin4(H1);
    asm volatile("s_waitcnt vmcnt(0)" ::: "memory");
    __builtin_amdgcn_sched_barrier(0);

    // stage A: sets 0..3 from LDS, set 4 from registers -> sge/sgo
    #pragma unroll
    for (int s = 0; s < 5; ++s) {
        float4 a, b;
        if (s < 4) {
            a = *reinterpret_cast<const float4*>(&xls[wv][2*s][lane][0]);
            b = *reinterpret_cast<const float4*>(&xls[wv][2*s+1][lane][0]);
        } else {
            a = H0; b = H1;
        }
        u32x4 bw;
        bw.x = cvt_pk_bf16(a.x, a.y); bw.y = cvt_pk_bf16(a.z, a.w);
        bw.z = cvt_pk_bf16(b.x, b.y); bw.w = cvt_pk_bf16(b.z, b.w);
        const bf16x8 Bx = __builtin_bit_cast(bf16x8, bw);

        f32x4 de_ = __builtin_amdgcn_mfma_f32_16x16x32_bf16(Ae, Bx, zero, 0, 0, 0);
        f32x4 do_ = __builtin_amdgcn_mfma_f32_16x16x32_bf16(Ao, Bx, zero, 0, 0, 0);

        const uint32_t e0 = cvt_pk_bf16(lrelu(de_[0]), lrelu(de_[1]));
        const uint32_t e1 = cvt_pk_bf16(lrelu(de_[2]), lrelu(de_[3]));
        const uint32_t o0 = cvt_pk_bf16(lrelu(do_[0]), lrelu(do_[1]));
        const uint32_t o1 = cvt_pk_bf16(lrelu(do_[2]), lrelu(do_[3]));

        const int elem = 256*s + 16*c + 4*g;      // pos - (W-4)
        *reinterpret_cast<uint2*>(&sge[wv][elem]) = make_uint2(e0, e1);
        *reinterpret_cast<uint2*>(&sgo[wv][elem]) = make_uint2(o0, o1);
    }

    // stage B: batch all LDS reads, then MFMAs, then stores
    u32x4 RG[4], RO[4];
    #pragma unroll
    for (int s = 0; s < 4; ++s) {
        const int elem = 256*s + 16*c + 8*g;
        RG[s] = *reinterpret_cast<const u32x4*>(&sge[wv][elem]);
        RO[s] = *reinterpret_cast<const u32x4*>(&sgo[wv][elem]);
    }
    #pragma unroll
    for (int s = 0; s < 4; ++s) {
        const bf16x8 Bg = __builtin_bit_cast(bf16x8, RG[s]);
        const bf16x8 Bo = __builtin_bit_cast(bf16x8, RO[s]);
        f32x4 dz = __builtin_amdgcn_mfma_f32_16x16x32_bf16(Ade, Bg, zero, 0, 0, 0);
        dz       = __builtin_amdgcn_mfma_f32_16x16x32_bf16(Add, Bo, dz,   0, 0, 0);
        *reinterpret_cast<float4*>(orow + W + 256*s + 16*c + 4*g) =
            make_float4(dz[0], dz[1], dz[2], dz[3]);
    }
}

extern "C" void kernel_launch(void* const* d_in, const int* in_sizes, int n_in,
                              void* d_out, int out_size, void* d_ws, size_t ws_size,
                              hipStream_t stream) {
    const float* x  = (const float*)d_in[0];
    const float* up = (const float*)d_in[1];
    const float* dn = (const float*)d_in[2];
    float* out      = (float*)d_out;
    uint32_t* ws    = (uint32_t*)d_ws;

    build_afrags<<<1, 64, 0, stream>>>(up, dn, ws);

    const int rows   = in_sizes[0] / T_LEN;      // 2048
    const int blocks = rows * 8;                 // 4096 outputs per block
    flrelu_mfma3<<<blocks, 256, 0, stream>>>(x, up, dn, ws, out);
}

// Round 23
// 108.817 us; speedup vs baseline: 2.4133x; 1.3925x over previous
//
#include <hip/hip_runtime.h>
#include <stdint.h>

// FilteredLReLU: up2(17-tap) -> *2 -> lrelu(0.01) -> down2(17-tap), fused.
// pk_fma SWAR (R17 base) + WAVE-level sharing of packed f16 intermediate
// pairs via per-wave LDS (no __syncthreads -- same verified wave-internal
// ds ordering as the R20-22 MFMA kernels, which allocated 40 VGPRs and
// passed; the block-barrier kernels R18/R19 were the allocator-pathology
// shape, avoided here).
//   Each lane: 4 own ga + 4 own go pairs (from 4 x-float4), write LDS at
//   16B lane stride; halo pairs read from slot lane+1; lane 63 computes
//   slot 64. All lanes (incl. row edges) use the masked-pair path.
//
//   ge[m] = lrelu( sum fe[j]*x[m-4+j] ), go[m] = lrelu( sum fo[j]*x[m-3+j] )
//   z[t]  = sum de[j]*ge[t-4+j] + sum dd[j]*go[t-4+j]   (UP gain in fe/fo)

#define T_LEN 32768
#define R_OUT 8

typedef __fp16   cvt2 __attribute__((ext_vector_type(2)));  // pkrtz result
typedef _Float16 hpair __attribute__((ext_vector_type(2))); // arithmetic

__device__ __forceinline__ uint32_t pkrtz(float lo, float hi) {
    cvt2 p = __builtin_amdgcn_cvt_pkrtz(lo, hi);
    return __builtin_bit_cast(uint32_t, p);
}
__device__ __forceinline__ hpair h2(uint32_t u) {
    return __builtin_bit_cast(hpair, u);
}
__device__ __forceinline__ uint32_t u32(hpair h) {
    return __builtin_bit_cast(uint32_t, h);
}
__device__ __forceinline__ hpair pk_fma(hpair a, hpair b, hpair c) {
    return __builtin_elementwise_fma(a, b, c);
}
__device__ __forceinline__ hpair pk_lrelu(hpair v, hpair c01) {
    return __builtin_elementwise_max(v, v * c01);
}

// ---- setup: broadcast tap pairs once into ws[0..33] ----
// ws[0..8]=feB, ws[9..16]=foB, ws[17..25]=deB, ws[26..33]=ddB
__global__ void pack_taps(const float* __restrict__ up,
                          const float* __restrict__ dn,
                          uint32_t* __restrict__ ws) {
    if (threadIdx.x == 0 && blockIdx.x == 0) {
        #pragma unroll
        for (int j = 0; j < 9; ++j) {
            float fe = 2.0f * up[2*j];
            float de = dn[2*j];
            ws[j]      = pkrtz(fe, fe);
            ws[17 + j] = pkrtz(de, de);
        }
        #pragma unroll
        for (int j = 0; j < 8; ++j) {
            float fo = 2.0f * up[2*j+1];
            float dd = dn[2*j+1];
            ws[9 + j]  = pkrtz(fo, fo);
            ws[26 + j] = pkrtz(dd, dd);
        }
    }
}

// compute 4 (ga, go) pairs for output base tb from xv[16] = x[tb-8 .. tb+7]
__device__ __forceinline__ void pairs4(
    const float* xv, const hpair* feB, const hpair* foB, hpair c01,
    uint32_t* ga, uint32_t* go)
{
    uint32_t xau[8], xsu[7];
    #pragma unroll
    for (int k = 0; k < 8; ++k) xau[k] = pkrtz(xv[2*k], xv[2*k+1]);
    #pragma unroll
    for (int k = 0; k < 7; ++k)
        xsu[k] = (xau[k] >> 16) | (xau[k+1] << 16);   // v_alignbit_b32

    #pragma unroll
    for (int q = 0; q < 4; ++q) {
        hpair s = feB[0] * h2(xau[q]);
        #pragma unroll
        for (int a = 1; a < 5; ++a) s = pk_fma(feB[2*a], h2(xau[q+a]), s);
        #pragma unroll
        for (int a = 0; a < 4; ++a) s = pk_fma(feB[2*a+1], h2(xsu[q+a]), s);
        ga[q] = u32(pk_lrelu(s, c01));

        hpair r = foB[0] * h2(xsu[q]);
        #pragma unroll
        for (int a = 1; a < 4; ++a) r = pk_fma(foB[2*a], h2(xsu[q+a]), r);
        #pragma unroll
        for (int a = 0; a < 4; ++a) r = pk_fma(foB[2*a+1], h2(xau[q+a+1]), r);
        go[q] = u32(pk_lrelu(r, c01));
    }
}

__global__ void flrelu_wshare(
    const float* __restrict__ x,
    const uint32_t* __restrict__ tw,
    float* __restrict__ out)
{
    __shared__ __align__(16) uint32_t sga[4][66][4];   // per-wave, 65 slots used
    __shared__ __align__(16) uint32_t sgb[4][66][4];

    const int tid  = threadIdx.x;
    const int lane = tid & 63;
    const int wv   = tid >> 6;
    const int gid  = blockIdx.x * 256 + tid;
    const int row  = gid >> 12;                 // 4096 threads per row
    const int t    = (gid & 4095) * R_OUT;
    const float* __restrict__ xrow = x + (size_t)row * T_LEN;
    float* __restrict__ orow       = out + (size_t)row * T_LEN;

    // taps: uniform pointer + const idx -> s_loads
    hpair feB[9], foB[8], deB[9], ddB[8];
    #pragma unroll
    for (int j = 0; j < 9; ++j) { feB[j] = h2(tw[j]); deB[j] = h2(tw[17+j]); }
    #pragma unroll
    for (int j = 0; j < 8; ++j) { foB[j] = h2(tw[9+j]); ddB[j] = h2(tw[26+j]); }
    const hpair c01 = h2(pkrtz(0.01f, 0.01f));

    // ---- own 4 ga + 4 go pairs ----
    uint32_t ga[4], go[4];
    {
        float xv[16];   // x[t-8 .. t+7]; t+7 always < T_LEN
        if (t >= 8) {
            const float4* xp = reinterpret_cast<const float4*>(xrow + t - 8);
            float4 v0 = xp[0], v1 = xp[1], v2 = xp[2], v3 = xp[3];
            xv[0]=v0.x; xv[1]=v0.y; xv[2]=v0.z; xv[3]=v0.w;
            xv[4]=v1.x; xv[5]=v1.y; xv[6]=v1.z; xv[7]=v1.w;
            xv[8]=v2.x; xv[9]=v2.y; xv[10]=v2.z; xv[11]=v2.w;
            xv[12]=v3.x; xv[13]=v3.y; xv[14]=v3.z; xv[15]=v3.w;
        } else {
            #pragma unroll
            for (int i = 0; i < 16; ++i) {
                int g = t - 8 + i;
                xv[i] = (g >= 0) ? xrow[g] : 0.0f;
            }
        }
        pairs4(xv, feB, foB, c01, ga, go);
        if (t == 0) {   // ge/go[m]=0 for m<0 (dn conv zero-pads y): q=0,1
            ga[0] = 0u; go[0] = 0u; ga[1] = 0u; go[1] = 0u;
        }
        *reinterpret_cast<uint4*>(&sga[wv][lane][0]) =
            make_uint4(ga[0], ga[1], ga[2], ga[3]);
        *reinterpret_cast<uint4*>(&sgb[wv][lane][0]) =
            make_uint4(go[0], go[1], go[2], go[3]);
    }

    // ---- lane 63: halo slot 64 (pairs for base tx = t+8) ----
    if (lane == 63) {
        const int tx = t + R_OUT;
        float xv[16];   // x[tx-8 .. tx+7] = x[t .. t+15]; low side always >= 0
        if (tx + 7 < T_LEN) {
            const float4* xp = reinterpret_cast<const float4*>(xrow + tx - 8);
            float4 v0 = xp[0], v1 = xp[1], v2 = xp[2], v3 = xp[3];
            xv[0]=v0.x; xv[1]=v0.y; xv[2]=v0.z; xv[3]=v0.w;
            xv[4]=v1.x; xv[5]=v1.y; xv[6]=v1.z; xv[7]=v1.w;
            xv[8]=v2.x; xv[9]=v2.y; xv[10]=v2.z; xv[11]=v2.w;
            xv[12]=v3.x; xv[13]=v3.y; xv[14]=v3.z; xv[15]=v3.w;
        } else {
            #pragma unroll
            for (int i = 0; i < 16; ++i) {
                int g = tx - 8 + i;
                xv[i] = (g < T_LEN) ? xrow[g] : 0.0f;
            }
        }
        uint32_t ha[4], hb[4];
        pairs4(xv, feB, foB, c01, ha, hb);
        if (tx + 3 >= T_LEN) {   // mask pairs with m >= T_LEN (last wave)
            #pragma unroll
            for (int q = 0; q < 4; ++q) {
                int m0 = tx - 4 + 2*q;
                uint32_t msk = ((m0   < T_LEN) ? 0x0000FFFFu : 0u)
                             | ((m0+1 < T_LEN) ? 0xFFFF0000u : 0u);
                ha[q] &= msk; hb[q] &= msk;
            }
        }
        *reinterpret_cast<uint4*>(&sga[wv][64][0]) =
            make_uint4(ha[0], ha[1], ha[2], ha[3]);
        *reinterpret_cast<uint4*>(&sgb[wv][64][0]) =
            make_uint4(hb[0], hb[1], hb[2], hb[3]);
    }

    // ---- stage B: own pairs (regs) + neighbor pairs (LDS slot lane+1) ----
    {
        uint4 GN = *reinterpret_cast<const uint4*>(&sga[wv][lane + 1][0]);
        uint4 ON = *reinterpret_cast<const uint4*>(&sgb[wv][lane + 1][0]);
        uint32_t gaF[8] = {ga[0], ga[1], ga[2], ga[3], GN.x, GN.y, GN.z, GN.w};
        uint32_t goF[8] = {go[0], go[1], go[2], go[3], ON.x, ON.y, ON.z, ON.w};

        uint32_t gs[7], gos[7];
        #pragma unroll
        for (int k = 0; k < 7; ++k) {
            gs[k]  = (gaF[k] >> 16) | (gaF[k+1] << 16);
            gos[k] = (goF[k] >> 16) | (goF[k+1] << 16);
        }

        hpair zp[4];
        #pragma unroll
        for (int p = 0; p < 4; ++p) {
            hpair s = deB[0] * h2(gaF[p]);
            #pragma unroll
            for (int a = 1; a < 5; ++a) s = pk_fma(deB[2*a], h2(gaF[p+a]), s);
            #pragma unroll
            for (int a = 0; a < 4; ++a) s = pk_fma(deB[2*a+1], h2(gs[p+a]), s);
            #pragma unroll
            for (int a = 0; a < 4; ++a) s = pk_fma(ddB[2*a], h2(goF[p+a]), s);
            #pragma unroll
            for (int a = 0; a < 4; ++a) s = pk_fma(ddB[2*a+1], h2(gos[p+a]), s);
            zp[p] = s;
        }

        float4* op = reinterpret_cast<float4*>(orow + t);
        op[0] = make_float4((float)zp[0][0], (float)zp[0][1],
                            (float)zp[1][0], (float)zp[1][1]);
        op[1] = make_float4((float)zp[2][0], (float)zp[2][1],
                            (float)zp[3][0], (float)zp[3][1]);
    }
}

extern "C" void kernel_launch(void* const* d_in, const int* in_sizes, int n_in,
                              void* d_out, int out_size, void* d_ws, size_t ws_size,
                              hipStream_t stream) {
    const float* x  = (const float*)d_in[0];
    const float* up = (const float*)d_in[1];
    const float* dn = (const float*)d_in[2];
    float* out      = (float*)d_out;
    uint32_t* ws    = (uint32_t*)d_ws;

    pack_taps<<<1, 64, 0, stream>>>(up, dn, ws);

    const int rows    = in_sizes[0] / T_LEN;         // 2048
    const int threads = rows * (T_LEN / R_OUT);      // 8.39M
    flrelu_wshare<<<threads / 256, 256, 0, stream>>>(x, ws, out);
}

// Round 24
// 106.794 us; speedup vs baseline: 2.4590x; 1.0189x over previous
//
#include <hip/hip_runtime.h>
#include <stdint.h>

// FilteredLReLU: up2(17-tap) -> *2 -> lrelu(0.01) -> down2(17-tap), fused.
// R23 wave-shared pk_fma SWAR + DISTRIBUTED halo: lanes 60..63 each
// compute ONE halo pair (~35 masked ops) instead of lane 63 computing all
// four (~90 masked ops on the wave critical path).
//
//   ge[m] = lrelu( sum fe[j]*x[m-4+j] ), go[m] = lrelu( sum fo[j]*x[m-3+j] )
//   z[t]  = sum de[j]*ge[t-4+j] + sum dd[j]*go[t-4+j]   (UP gain in fe/fo)

#define T_LEN 32768
#define R_OUT 8

typedef __fp16   cvt2 __attribute__((ext_vector_type(2)));  // pkrtz result
typedef _Float16 hpair __attribute__((ext_vector_type(2))); // arithmetic

__device__ __forceinline__ uint32_t pkrtz(float lo, float hi) {
    cvt2 p = __builtin_amdgcn_cvt_pkrtz(lo, hi);
    return __builtin_bit_cast(uint32_t, p);
}
__device__ __forceinline__ hpair h2(uint32_t u) {
    return __builtin_bit_cast(hpair, u);
}
__device__ __forceinline__ uint32_t u32(hpair h) {
    return __builtin_bit_cast(uint32_t, h);
}
__device__ __forceinline__ hpair pk_fma(hpair a, hpair b, hpair c) {
    return __builtin_elementwise_fma(a, b, c);
}
__device__ __forceinline__ hpair pk_lrelu(hpair v, hpair c01) {
    return __builtin_elementwise_max(v, v * c01);
}

// ---- setup: broadcast tap pairs once into ws[0..33] ----
// ws[0..8]=feB, ws[9..16]=foB, ws[17..25]=deB, ws[26..33]=ddB
__global__ void pack_taps(const float* __restrict__ up,
                          const float* __restrict__ dn,
                          uint32_t* __restrict__ ws) {
    if (threadIdx.x == 0 && blockIdx.x == 0) {
        #pragma unroll
        for (int j = 0; j < 9; ++j) {
            float fe = 2.0f * up[2*j];
            float de = dn[2*j];
            ws[j]      = pkrtz(fe, fe);
            ws[17 + j] = pkrtz(de, de);
        }
        #pragma unroll
        for (int j = 0; j < 8; ++j) {
            float fo = 2.0f * up[2*j+1];
            float dd = dn[2*j+1];
            ws[9 + j]  = pkrtz(fo, fo);
            ws[26 + j] = pkrtz(dd, dd);
        }
    }
}

// compute 4 (ga, go) pairs for output base tb from xv[16] = x[tb-8 .. tb+7]
__device__ __forceinline__ void pairs4(
    const float* xv, const hpair* feB, const hpair* foB, hpair c01,
    uint32_t* ga, uint32_t* go)
{
    uint32_t xau[8], xsu[7];
    #pragma unroll
    for (int k = 0; k < 8; ++k) xau[k] = pkrtz(xv[2*k], xv[2*k+1]);
    #pragma unroll
    for (int k = 0; k < 7; ++k)
        xsu[k] = (xau[k] >> 16) | (xau[k+1] << 16);   // v_alignbit_b32

    #pragma unroll
    for (int q = 0; q < 4; ++q) {
        hpair s = feB[0] * h2(xau[q]);
        #pragma unroll
        for (int a = 1; a < 5; ++a) s = pk_fma(feB[2*a], h2(xau[q+a]), s);
        #pragma unroll
        for (int a = 0; a < 4; ++a) s = pk_fma(feB[2*a+1], h2(xsu[q+a]), s);
        ga[q] = u32(pk_lrelu(s, c01));

        hpair r = foB[0] * h2(xsu[q]);
        #pragma unroll
        for (int a = 1; a < 4; ++a) r = pk_fma(foB[2*a], h2(xsu[q+a]), r);
        #pragma unroll
        for (int a = 0; a < 4; ++a) r = pk_fma(foB[2*a+1], h2(xau[q+a+1]), r);
        go[q] = u32(pk_lrelu(r, c01));
    }
}

__global__ void flrelu_wshare2(
    const float* __restrict__ x,
    const uint32_t* __restrict__ tw,
    float* __restrict__ out)
{
    __shared__ __align__(16) uint32_t sga[4][66][4];   // per-wave, 65 slots used
    __shared__ __align__(16) uint32_t sgb[4][66][4];

    const int tid  = threadIdx.x;
    const int lane = tid & 63;
    const int wv   = tid >> 6;
    const int gid  = blockIdx.x * 256 + tid;
    const int row  = gid >> 12;                 // 4096 threads per row
    const int t    = (gid & 4095) * R_OUT;
    const float* __restrict__ xrow = x + (size_t)row * T_LEN;
    float* __restrict__ orow       = out + (size_t)row * T_LEN;

    // taps: uniform pointer + const idx -> s_loads
    hpair feB[9], foB[8], deB[9], ddB[8];
    #pragma unroll
    for (int j = 0; j < 9; ++j) { feB[j] = h2(tw[j]); deB[j] = h2(tw[17+j]); }
    #pragma unroll
    for (int j = 0; j < 8; ++j) { foB[j] = h2(tw[9+j]); ddB[j] = h2(tw[26+j]); }
    const hpair c01 = h2(pkrtz(0.01f, 0.01f));

    // ---- own 4 ga + 4 go pairs ----
    uint32_t ga[4], go[4];
    {
        float xv[16];   // x[t-8 .. t+7]; t+7 always < T_LEN
        if (t >= 8) {
            const float4* xp = reinterpret_cast<const float4*>(xrow + t - 8);
            float4 v0 = xp[0], v1 = xp[1], v2 = xp[2], v3 = xp[3];
            xv[0]=v0.x; xv[1]=v0.y; xv[2]=v0.z; xv[3]=v0.w;
            xv[4]=v1.x; xv[5]=v1.y; xv[6]=v1.z; xv[7]=v1.w;
            xv[8]=v2.x; xv[9]=v2.y; xv[10]=v2.z; xv[11]=v2.w;
            xv[12]=v3.x; xv[13]=v3.y; xv[14]=v3.z; xv[15]=v3.w;
        } else {
            #pragma unroll
            for (int i = 0; i < 16; ++i) {
                int g = t - 8 + i;
                xv[i] = (g >= 0) ? xrow[g] : 0.0f;
            }
        }
        pairs4(xv, feB, foB, c01, ga, go);
        if (t == 0) {   // ge/go[m]=0 for m<0 (dn conv zero-pads y): q=0,1
            ga[0] = 0u; go[0] = 0u; ga[1] = 0u; go[1] = 0u;
        }
        *reinterpret_cast<uint4*>(&sga[wv][lane][0]) =
            make_uint4(ga[0], ga[1], ga[2], ga[3]);
        *reinterpret_cast<uint4*>(&sgb[wv][lane][0]) =
            make_uint4(go[0], go[1], go[2], go[3]);
    }

    // ---- halo slot 64: lanes 60..63 compute ONE pair each (q = lane-60) ----
    if (lane >= 60) {
        const int q  = lane - 60;
        const int tx = (t - lane * R_OUT) + 512;   // wave halo base; <= T_LEN
        // window: x[tx-8+2q .. tx+3+2q], 12 floats, 8B-aligned (2q even)
        float xw[12];
        if (tx + 2*q + 3 < T_LEN) {
            const float2* xp2 =
                reinterpret_cast<const float2*>(xrow + tx - 8 + 2*q);
            #pragma unroll
            for (int k = 0; k < 6; ++k) {
                float2 v = xp2[k];
                xw[2*k] = v.x; xw[2*k+1] = v.y;
            }
        } else {
            #pragma unroll
            for (int i = 0; i < 12; ++i) {
                int g = tx - 8 + 2*q + i;
                xw[i] = (g < T_LEN) ? xrow[g] : 0.0f;
            }
        }
        uint32_t xau[5], xsu[4];
        #pragma unroll
        for (int k = 0; k < 5; ++k) xau[k] = pkrtz(xw[2*k], xw[2*k+1]);
        #pragma unroll
        for (int k = 0; k < 4; ++k)
            xsu[k] = (xau[k] >> 16) | (xau[k+1] << 16);

        hpair s = feB[0] * h2(xau[0]);
        #pragma unroll
        for (int a = 1; a < 5; ++a) s = pk_fma(feB[2*a], h2(xau[a]), s);
        #pragma unroll
        for (int a = 0; a < 4; ++a) s = pk_fma(feB[2*a+1], h2(xsu[a]), s);
        uint32_t ha = u32(pk_lrelu(s, c01));

        hpair r = foB[0] * h2(xsu[0]);
        #pragma unroll
        for (int a = 1; a < 4; ++a) r = pk_fma(foB[2*a], h2(xsu[a]), r);
        #pragma unroll
        for (int a = 0; a < 4; ++a) r = pk_fma(foB[2*a+1], h2(xau[a+1]), r);
        uint32_t hb = u32(pk_lrelu(r, c01));

        const int m0 = tx - 4 + 2*q;             // >= 508, may exceed T_LEN
        const uint32_t msk = ((m0   < T_LEN) ? 0x0000FFFFu : 0u)
                           | ((m0+1 < T_LEN) ? 0xFFFF0000u : 0u);
        sga[wv][64][q] = ha & msk;
        sgb[wv][64][q] = hb & msk;
    }

    // ---- stage B: own pairs (regs) + neighbor pairs (LDS slot lane+1) ----
    {
        uint4 GN = *reinterpret_cast<const uint4*>(&sga[wv][lane + 1][0]);
        uint4 ON = *reinterpret_cast<const uint4*>(&sgb[wv][lane + 1][0]);
        uint32_t gaF[8] = {ga[0], ga[1], ga[2], ga[3], GN.x, GN.y, GN.z, GN.w};
        uint32_t goF[8] = {go[0], go[1], go[2], go[3], ON.x, ON.y, ON.z, ON.w};

        uint32_t gs[7], gos[7];
        #pragma unroll
        for (int k = 0; k < 7; ++k) {
            gs[k]  = (gaF[k] >> 16) | (gaF[k+1] << 16);
            gos[k] = (goF[k] >> 16) | (goF[k+1] << 16);
        }

        hpair zp[4];
        #pragma unroll
        for (int p = 0; p < 4; ++p) {
            hpair s = deB[0] * h2(gaF[p]);
            #pragma unroll
            for (int a = 1; a < 5; ++a) s = pk_fma(deB[2*a], h2(gaF[p+a]), s);
            #pragma unroll
            for (int a = 0; a < 4; ++a) s = pk_fma(deB[2*a+1], h2(gs[p+a]), s);
            #pragma unroll
            for (int a = 0; a < 4; ++a) s = pk_fma(ddB[2*a], h2(goF[p+a]), s);
            #pragma unroll
            for (int a = 0; a < 4; ++a) s = pk_fma(ddB[2*a+1], h2(gos[p+a]), s);
            zp[p] = s;
        }

        float4* op = reinterpret_cast<float4*>(orow + t);
        op[0] = make_float4((float)zp[0][0], (float)zp[0][1],
                            (float)zp[1][0], (float)zp[1][1]);
        op[1] = make_float4((float)zp[2][0], (float)zp[2][1],
                            (float)zp[3][0], (float)zp[3][1]);
    }
}

extern "C" void kernel_launch(void* const* d_in, const int* in_sizes, int n_in,
                              void* d_out, int out_size, void* d_ws, size_t ws_size,
                              hipStream_t stream) {
    const float* x  = (const float*)d_in[0];
    const float* up = (const float*)d_in[1];
    const float* dn = (const float*)d_in[2];
    float* out      = (float*)d_out;
    uint32_t* ws    = (uint32_t*)d_ws;

    pack_taps<<<1, 64, 0, stream>>>(up, dn, ws);

    const int rows    = in_sizes[0] / T_LEN;         // 2048
    const int threads = rows * (T_LEN / R_OUT);      // 8.39M
    flrelu_wshare2<<<threads / 256, 256, 0, stream>>>(x, ws, out);
}